// Round 7
// baseline (1272.282 us; speedup 1.0000x reference)
//
#include <hip/hip_runtime.h>
#include <math.h>

typedef unsigned int u32;
typedef unsigned short u16;

#define NS 128          // T-1 timesteps
#define A_ 5
#define B_ 128
#define NTH 256
#define NWG 160         // 5 agents x 32 chunks of 4 rows
#define LOG2PI_F 1.8378770664093453f

// ---- packed weight layout (uint2 = 4 f16 units), per agent ----
#define OF_E1 0         // 40q x 128
#define OF_P1 5120
#define OF_D1 10240
#define OF_G  15360     // 40q x 384 (3 gates x 128)
#define OF_E2 30720     // 32q x 128
#define OF_P2 34816
#define OF_D2 38912
#define OF_H  43008     // 4 heads x (32q x 16)
#define OF_DH 45056     // 2 heads x (32q x 2)
#define AGU2  45184

typedef _Float16 half2v __attribute__((ext_vector_type(2)));

__device__ __forceinline__ float fdot2(u32 w, u32 x, float acc) {
#if __has_builtin(__builtin_amdgcn_fdot2)
    return __builtin_amdgcn_fdot2(__builtin_bit_cast(half2v, w),
                                  __builtin_bit_cast(half2v, x), acc, false);
#else
    half2v a = __builtin_bit_cast(half2v, w), b = __builtin_bit_cast(half2v, x);
    return acc + (float)a.x * (float)b.x + (float)a.y * (float)b.y;
#endif
}
__device__ __forceinline__ u16 f2h(float f) { _Float16 h = (_Float16)f; return __builtin_bit_cast(u16, h); }
__device__ __forceinline__ float h2f(u16 u) { return (float)__builtin_bit_cast(_Float16, u); }
__device__ __forceinline__ float softplusf_(float x) { return fmaxf(x, 0.f) + log1pf(expf(-fabsf(x))); }
__device__ __forceinline__ float sigmoidf_(float x) { return 1.f / (1.f + expf(-x)); }

#define RED32(v) { v += __shfl_xor(v, 32); }
#define PINU2(w) asm volatile("" : "+v"((w).x), "+v"((w).y))

struct P7s {
    const float* __restrict__ y;
    const float* __restrict__ eps;
    const float* __restrict__ eb1; const float* __restrict__ eb2;
    const float* __restrict__ pb1; const float* __restrict__ pb2;
    const float* __restrict__ db1; const float* __restrict__ db2;
    const float* __restrict__ emb; const float* __restrict__ esb;
    const float* __restrict__ pmb; const float* __restrict__ psb;
    const float* __restrict__ dmb; const float* __restrict__ dsb;
    const float* __restrict__ bih; const float* __restrict__ bhh;
    const uint2* __restrict__ wq;
    float* __restrict__ partials;
};

// Occupancy rule fit to R4/R5/R6 evidence: effective min waves/SIMD =
// max(declared, waves_per_wg/4); VGPR cap = 256/min_waves. 256 threads = 4
// waves -> 1 wave/SIMD -> 256 VGPR cap. 155KB LDS also forces 1 wg/CU.
__global__ void __launch_bounds__(NTH, 1) vrnn7(P7s p) {
    const int tid = threadIdx.x;
    const int a = blockIdx.x >> 5;
    const int b0 = (blockIdx.x & 31) * 4;
    const int wave = tid >> 6;               // 0..3
    const int lane = tid & 63;
    const int o = wave * 32 + (lane & 31);   // output column 0..127
    const int k2 = lane >> 5;                // K half 0..1
    const bool k0 = (k2 == 0);

    __shared__ __align__(16) u16 U[4][160];          // [x2 y10 z16 pad4 h128]
    __shared__ __align__(16) u16 aA[4][128], aB[4][128], aC[4][128], aD[4][128];
    __shared__ float mue[4][16], sde[4][16], mup[4][16], sdp[4][16];
    __shared__ float xf[4][2], dmu[4][2], dsd[4][2];
    __shared__ uint2 Gl[15360];        // GRU weights [q40][gate384], 123KB
    __shared__ __align__(16) uint2 whT[4 * 544];     // heads [head][zd][q32 +2pad]
    __shared__ uint2 wdh[128];
    __shared__ float bE1L[128], bP1L[128], bD1L[128];
    __shared__ float bE2L[128], bP2L[128], bD2L[128];
    __shared__ float bIHL[384], bHHL[384];
    __shared__ float bHl[64], bDHl[4];
    __shared__ float red[NTH];

    const uint2* WA = p.wq + (size_t)a * AGU2;

    // ---- one-time init ----
    for (int i = tid; i < 15360; i += NTH) Gl[i] = WA[OF_G + i];
    for (int i = tid; i < 2048; i += NTH) {
        int hh = i >> 9, rem = i & 511, q = rem >> 4, zd = rem & 15;
        whT[hh * 544 + zd * 34 + q] = WA[OF_H + i];
    }
    if (tid < 128) {
        wdh[tid] = WA[OF_DH + tid];
        bE1L[tid] = p.eb1[a * 128 + tid]; bE2L[tid] = p.eb2[a * 128 + tid];
        bP1L[tid] = p.pb1[a * 128 + tid]; bP2L[tid] = p.pb2[a * 128 + tid];
        bD1L[tid] = p.db1[a * 128 + tid]; bD2L[tid] = p.db2[a * 128 + tid];
    }
    for (int i = tid; i < 384; i += NTH) {
        bIHL[i] = p.bih[a * 384 + i]; bHHL[i] = p.bhh[a * 384 + i];
    }
    if (tid < 64) {
        int h = tid >> 4, c = tid & 15;
        bHl[tid] = ((h == 0) ? p.emb : (h == 1) ? p.esb : (h == 2) ? p.pmb : p.psb)[a * 16 + c];
    }
    if (tid < 4) bDHl[tid] = (tid < 2) ? p.dmb[a * 2 + tid] : p.dsb[a * 2 + (tid - 2)];
    for (int i = tid; i < 640; i += NTH) ((u16*)U)[i] = 0;

    // ---- register-resident weights (k2 halves, pinned) ----
    uint2 wE1[20], wP1[20], wD1[20];
    uint2 wE2[16], wP2[16], wD2[16];
#pragma unroll
    for (int j = 0; j < 20; ++j) {
        int q = k2 * 20 + j;
        wE1[j] = WA[OF_E1 + q * 128 + o];
        wP1[j] = WA[OF_P1 + q * 128 + o];
        wD1[j] = WA[OF_D1 + q * 128 + o];
    }
#pragma unroll
    for (int j = 0; j < 16; ++j) {
        int q = k2 * 16 + j;
        wE2[j] = WA[OF_E2 + q * 128 + o];
        wP2[j] = WA[OF_P2 + q * 128 + o];
        wD2[j] = WA[OF_D2 + q * 128 + o];
    }
#pragma unroll
    for (int j = 0; j < 20; ++j) { PINU2(wE1[j]); PINU2(wP1[j]); PINU2(wD1[j]); }
#pragma unroll
    for (int j = 0; j < 16; ++j) { PINU2(wE2[j]); PINU2(wP2[j]); PINU2(wD2[j]); }

    // ---- P4/P8 lane roles ----
    const int headH = wave, rowH = lane >> 4, zdH = lane & 15;   // P4: 4x4x16 = 256
    const int outD = wave * 4 + (lane >> 4), partD = lane & 15;  // P8
    const int headD = outD >> 3, subD = outD & 7, rD = subD >> 1, xdD = subD & 1;

    // ---- prefetch t=0 inputs ----
    const int ry = tid / 10, jy = tid - ry * 10;            // tid<40
    const int rx = (tid - 40) >> 1, xdx = (tid - 40) & 1;   // 40<=tid<48
    const int re = tid >> 4, ze = tid & 15;                 // tid<64
    float ypre = 0.f, xpre = 0.f, epre = 0.f;
    if (tid < 40) ypre = p.y[0 * (B_ * 10) + (b0 + ry) * 10 + jy];
    else if (tid < 48) xpre = p.y[1 * (B_ * 10) + (b0 + rx) * 10 + a * 2 + xdx];
    if (tid < 64) epre = p.eps[(((size_t)0 * A_ + a) * B_ + (b0 + re)) * 16 + ze];

    float kl_acc = 0.f, nll_acc = 0.f;
    float hn0 = 0.f, hn1 = 0.f;
    const int r0w = k2 * 2, r1w = r0w + 1;   // rows this lane writes

#pragma unroll 1
    for (int t = 0; t < NS; ++t) {
        const int tn = (t + 1 < NS) ? t + 1 : t;
        __syncthreads();
        // ---- P1: commit prefetched inputs, issue next prefetch ----
        if (tid < 40) {
            U[ry][2 + jy] = f2h(ypre);
            ypre = p.y[tn * (B_ * 10) + (b0 + ry) * 10 + jy];
        } else if (tid < 48) {
            U[rx][xdx] = f2h(xpre); xf[rx][xdx] = xpre;
            xpre = p.y[(tn + 1) * (B_ * 10) + (b0 + rx) * 10 + a * 2 + xdx];
        }
        __syncthreads();

        // ---- P2: enc1 + pri1 ----
        {
            float bE = k0 ? bE1L[o] : 0.f, bP = k0 ? bP1L[o] : 0.f;
            float aE[4], aP[4];
#pragma unroll
            for (int r = 0; r < 4; ++r) { aE[r] = bE; aP[r] = bP; }
#pragma unroll
            for (int jj = 0; jj < 10; ++jj) {
#pragma unroll
                for (int r = 0; r < 4; ++r) {
                    uint4 xv = *(const uint4*)(&U[r][0] + k2 * 80 + jj * 8);
                    aE[r] = fdot2(wE1[2*jj].x,   xv.x, aE[r]);
                    aE[r] = fdot2(wE1[2*jj].y,   xv.y, aE[r]);
                    aE[r] = fdot2(wE1[2*jj+1].x, xv.z, aE[r]);
                    aE[r] = fdot2(wE1[2*jj+1].y, xv.w, aE[r]);
                    aP[r] = fdot2(wP1[2*jj].x,   xv.x, aP[r]);
                    aP[r] = fdot2(wP1[2*jj].y,   xv.y, aP[r]);
                    aP[r] = fdot2(wP1[2*jj+1].x, xv.z, aP[r]);
                    aP[r] = fdot2(wP1[2*jj+1].y, xv.w, aP[r]);
                }
            }
#pragma unroll
            for (int r = 0; r < 4; ++r) { RED32(aE[r]); RED32(aP[r]); }
            float e0 = k2 ? aE[2] : aE[0], e1 = k2 ? aE[3] : aE[1];
            float q0 = k2 ? aP[2] : aP[0], q1 = k2 ? aP[3] : aP[1];
            aA[r0w][o] = f2h(fmaxf(e0, 0.f)); aA[r1w][o] = f2h(fmaxf(e1, 0.f));
            aC[r0w][o] = f2h(fmaxf(q0, 0.f)); aC[r1w][o] = f2h(fmaxf(q1, 0.f));
        }
        __syncthreads();

        // ---- P3: enc2 (aA->aB), pri2 (aC->aD) ----
        {
            float bE = k0 ? bE2L[o] : 0.f, bP = k0 ? bP2L[o] : 0.f;
            float aE[4], aP[4];
#pragma unroll
            for (int r = 0; r < 4; ++r) { aE[r] = bE; aP[r] = bP; }
#pragma unroll
            for (int jj = 0; jj < 8; ++jj) {
#pragma unroll
                for (int r = 0; r < 4; ++r) {
                    uint4 xa = *(const uint4*)(&aA[r][0] + k2 * 64 + jj * 8);
                    uint4 xc = *(const uint4*)(&aC[r][0] + k2 * 64 + jj * 8);
                    aE[r] = fdot2(wE2[2*jj].x,   xa.x, aE[r]);
                    aE[r] = fdot2(wE2[2*jj].y,   xa.y, aE[r]);
                    aE[r] = fdot2(wE2[2*jj+1].x, xa.z, aE[r]);
                    aE[r] = fdot2(wE2[2*jj+1].y, xa.w, aE[r]);
                    aP[r] = fdot2(wP2[2*jj].x,   xc.x, aP[r]);
                    aP[r] = fdot2(wP2[2*jj].y,   xc.y, aP[r]);
                    aP[r] = fdot2(wP2[2*jj+1].x, xc.z, aP[r]);
                    aP[r] = fdot2(wP2[2*jj+1].y, xc.w, aP[r]);
                }
            }
#pragma unroll
            for (int r = 0; r < 4; ++r) { RED32(aE[r]); RED32(aP[r]); }
            float e0 = k2 ? aE[2] : aE[0], e1 = k2 ? aE[3] : aE[1];
            float q0 = k2 ? aP[2] : aP[0], q1 = k2 ? aP[3] : aP[1];
            aB[r0w][o] = f2h(fmaxf(e0, 0.f)); aB[r1w][o] = f2h(fmaxf(e1, 0.f));
            aD[r0w][o] = f2h(fmaxf(q0, 0.f)); aD[r1w][o] = f2h(fmaxf(q1, 0.f));
        }
        __syncthreads();

        // ---- P4: 4 gaussian heads, full-K per thread, no shuffles ----
        {
            const u16* src = (headH < 2) ? &aB[rowH][0] : &aD[rowH][0];
            float e = bHl[headH * 16 + zdH];
#pragma unroll
            for (int jj = 0; jj < 16; ++jj) {
                uint4 w  = *(const uint4*)(&whT[headH * 544 + zdH * 34 + 2 * jj]);
                uint4 xv = *(const uint4*)(src + jj * 8);
                e = fdot2(w.x, xv.x, e); e = fdot2(w.y, xv.y, e);
                e = fdot2(w.z, xv.z, e); e = fdot2(w.w, xv.w, e);
            }
            if (headH == 0)      mue[rowH][zdH] = e;
            else if (headH == 1) sde[rowH][zdH] = softplusf_(e);
            else if (headH == 2) mup[rowH][zdH] = e;
            else                 sdp[rowH][zdH] = softplusf_(e);
        }
        __syncthreads();

        // ---- P5: z sample + KL ----
        if (tid < 64) {
            float em = mue[re][ze], es = sde[re][ze], pm = mup[re][ze], ps = sdp[re][ze];
            float zv = fmaf(epre, es, em);
            U[re][12 + ze] = f2h(zv);
            float dm = em - pm;
            kl_acc += 0.5f * (2.f * (logf(ps) - logf(es)) + (es * es + dm * dm) / (ps * ps) - 1.f);
            epre = p.eps[(((size_t)tn * A_ + a) * B_ + (b0 + re)) * 16 + ze];
        }
        __syncthreads();

        // ---- P6: dec1 (regs) + GRU (weights from LDS) ----
        {
            float bO  = k0 ? bD1L[o] : 0.f;
            float b0s = k0 ? (bIHL[o] + bHHL[o]) : 0.f;
            float b1s = k0 ? (bIHL[128 + o] + bHHL[128 + o]) : 0.f;
            float bgi = k0 ? bIHL[256 + o] : 0.f;
            float bgh = k0 ? bHHL[256 + o] : 0.f;
            float aO[4], s0[4], s1[4], gA[4], gB[4];
#pragma unroll
            for (int r = 0; r < 4; ++r) {
                aO[r] = bO; s0[r] = b0s; s1[r] = b1s; gA[r] = 0.f; gB[r] = 0.f;
            }
#pragma unroll
            for (int jj = 0; jj < 10; ++jj) {
                int q0 = k2 * 20 + 2 * jj;
                uint2 w00 = Gl[q0 * 384 + o],       w01 = Gl[(q0 + 1) * 384 + o];
                uint2 w10 = Gl[q0 * 384 + 128 + o], w11 = Gl[(q0 + 1) * 384 + 128 + o];
                uint2 w20 = Gl[q0 * 384 + 256 + o], w21 = Gl[(q0 + 1) * 384 + 256 + o];
#pragma unroll
                for (int r = 0; r < 4; ++r) {
                    uint4 xv = *(const uint4*)(&U[r][0] + k2 * 80 + jj * 8);
                    aO[r] = fdot2(wD1[2*jj].x,   xv.x, aO[r]);
                    aO[r] = fdot2(wD1[2*jj].y,   xv.y, aO[r]);
                    aO[r] = fdot2(wD1[2*jj+1].x, xv.z, aO[r]);
                    aO[r] = fdot2(wD1[2*jj+1].y, xv.w, aO[r]);
                    s0[r] = fdot2(w00.x, xv.x, s0[r]);
                    s0[r] = fdot2(w00.y, xv.y, s0[r]);
                    s0[r] = fdot2(w01.x, xv.z, s0[r]);
                    s0[r] = fdot2(w01.y, xv.w, s0[r]);
                    s1[r] = fdot2(w10.x, xv.x, s1[r]);
                    s1[r] = fdot2(w10.y, xv.y, s1[r]);
                    s1[r] = fdot2(w11.x, xv.z, s1[r]);
                    s1[r] = fdot2(w11.y, xv.w, s1[r]);
                    // jj<4 with k2==0 covers unified slots u<32 (the ih region)
                    float& g = (jj < 4) ? gA[r] : gB[r];
                    g = fdot2(w20.x, xv.x, g);
                    g = fdot2(w20.y, xv.y, g);
                    g = fdot2(w21.x, xv.z, g);
                    g = fdot2(w21.y, xv.w, g);
                }
            }
            float gi[4], gh[4];
#pragma unroll
            for (int r = 0; r < 4; ++r) {
                gi[r] = bgi + (k0 ? gA[r] : 0.f);
                gh[r] = bgh + (k0 ? gB[r] : (gA[r] + gB[r]));
                RED32(aO[r]); RED32(s0[r]); RED32(s1[r]); RED32(gi[r]); RED32(gh[r]);
            }
            float vO0 = k2 ? aO[2] : aO[0], vO1 = k2 ? aO[3] : aO[1];
            float rs0 = k2 ? s0[2] : s0[0], rs1 = k2 ? s0[3] : s0[1];
            float zs0 = k2 ? s1[2] : s1[0], zs1 = k2 ? s1[3] : s1[1];
            float gi0 = k2 ? gi[2] : gi[0], gi1 = k2 ? gi[3] : gi[1];
            float gh0 = k2 ? gh[2] : gh[0], gh1 = k2 ? gh[3] : gh[1];
            float rr0 = sigmoidf_(rs0), zz0 = sigmoidf_(zs0);
            float nn0 = tanhf(fmaf(rr0, gh0, gi0));
            float hold0 = h2f(U[r0w][32 + o]);
            hn0 = fmaf(zz0, hold0 - nn0, nn0);
            float rr1 = sigmoidf_(rs1), zz1 = sigmoidf_(zs1);
            float nn1 = tanhf(fmaf(rr1, gh1, gi1));
            float hold1 = h2f(U[r1w][32 + o]);
            hn1 = fmaf(zz1, hold1 - nn1, nn1);
            aA[r0w][o] = f2h(fmaxf(vO0, 0.f));
            aA[r1w][o] = f2h(fmaxf(vO1, 0.f));
        }
        __syncthreads();

        // ---- P7: dec2 (aA -> aB) + h state write ----
        U[r0w][32 + o] = f2h(hn0);
        U[r1w][32 + o] = f2h(hn1);
        {
            float bE = k0 ? bD2L[o] : 0.f;
            float aE[4];
#pragma unroll
            for (int r = 0; r < 4; ++r) aE[r] = bE;
#pragma unroll
            for (int jj = 0; jj < 8; ++jj) {
#pragma unroll
                for (int r = 0; r < 4; ++r) {
                    uint4 xa = *(const uint4*)(&aA[r][0] + k2 * 64 + jj * 8);
                    aE[r] = fdot2(wD2[2*jj].x,   xa.x, aE[r]);
                    aE[r] = fdot2(wD2[2*jj].y,   xa.y, aE[r]);
                    aE[r] = fdot2(wD2[2*jj+1].x, xa.z, aE[r]);
                    aE[r] = fdot2(wD2[2*jj+1].y, xa.w, aE[r]);
                }
            }
#pragma unroll
            for (int r = 0; r < 4; ++r) RED32(aE[r]);
            float e0 = k2 ? aE[2] : aE[0], e1 = k2 ? aE[3] : aE[1];
            aB[r0w][o] = f2h(fmaxf(e0, 0.f));
            aB[r1w][o] = f2h(fmaxf(e1, 0.f));
        }
        __syncthreads();

        // ---- P8: dec heads (128->2), 16 outputs x 16-lane K-split ----
        {
            uint4 xa = *(const uint4*)(&aB[rD][0] + partD * 8);
            uint2 w0 = wdh[headD * 64 + (partD * 2) * 2 + xdD];
            uint2 w1 = wdh[headD * 64 + (partD * 2 + 1) * 2 + xdD];
            float s = fdot2(w0.x, xa.x, 0.f);
            s = fdot2(w0.y, xa.y, s);
            s = fdot2(w1.x, xa.z, s);
            s = fdot2(w1.y, xa.w, s);
            s += __shfl_xor(s, 1); s += __shfl_xor(s, 2);
            s += __shfl_xor(s, 4); s += __shfl_xor(s, 8);
            if (partD == 0) {
                float v = bDHl[headD * 2 + xdD] + s;
                if (headD) dsd[rD][xdD] = softplusf_(v);
                else       dmu[rD][xdD] = v;
            }
        }
        __syncthreads();

        // ---- P9: NLL ----
        if (tid < 8) {
            int r = tid >> 1, xd = tid & 1;
            float d = xf[r][xd] - dmu[r][xd];
            float sd = dsd[r][xd];
            nll_acc += 0.5f * (d * d / (sd * sd) + 2.f * logf(sd) + LOG2PI_F);
        }
    }

    // ---- block reductions ----
    __syncthreads();
    red[tid] = kl_acc; __syncthreads();
    for (int s2 = NTH / 2; s2 > 0; s2 >>= 1) {
        if (tid < s2) red[tid] += red[tid + s2];
        __syncthreads();
    }
    if (tid == 0) p.partials[blockIdx.x] = red[0];
    __syncthreads();
    red[tid] = nll_acc; __syncthreads();
    for (int s2 = NTH / 2; s2 > 0; s2 >>= 1) {
        if (tid < s2) red[tid] += red[tid + s2];
        __syncthreads();
    }
    if (tid == 0) p.partials[NWG + blockIdx.x] = red[0];
}

// ---------------- prep: pack weights into unified zero-padded f16 quads ----------------
struct PrepP {
    const float* eW1; const float* pW1; const float* dW1;
    const float* wih; const float* whh;
    const float* eW2; const float* pW2; const float* dW2;
    const float* hW[4];   // em es pm ps
    const float* dHW[2];  // dm ds
    uint2* dst;
};

__global__ void prep3(PrepP pp) {
    const int jod[13]  = {128,128,128,384, 128,128,128, 16,16,16,16, 2,2};
    const int jnq[13]  = {40,40,40,40, 32,32,32, 32,32,32,32, 32,32};
    const int jdst[13] = {OF_E1,OF_P1,OF_D1,OF_G, OF_E2,OF_P2,OF_D2,
                          OF_H,OF_H+512,OF_H+1024,OF_H+1536, OF_DH,OF_DH+64};
    const int jkt[3]   = {140,138,154};

    int job = blockIdx.y;
    int od = jod[job], nq = jnq[job];
    int total = A_ * nq * od;
    int idx = blockIdx.x * 256 + threadIdx.x;
    if (idx >= total) return;
    int a = idx / (nq * od);
    int rem = idx - a * (nq * od);
    int q = rem / od;
    int c = rem - q * od;

    float v[4];
#pragma unroll
    for (int i = 0; i < 4; ++i) {
        int k = 4 * q + i;
        float val = 0.f;
        if (job < 3) {
            int sk = -1;
            if (job == 0)      sk = (k < 12) ? k : (k >= 32 ? k - 20 : -1);
            else if (job == 1) sk = (k >= 2 && k < 12) ? k - 2 : (k >= 32 ? k - 22 : -1);
            else               sk = (k >= 2 && k < 28) ? k - 2 : (k >= 32 ? k - 6 : -1);
            const float* s = (job == 0) ? pp.eW1 : (job == 1) ? pp.pW1 : pp.dW1;
            if (sk >= 0) val = s[((size_t)a * jkt[job] + sk) * 128 + c];
        } else if (job == 3) {
            if (k < 2)                  val = pp.wih[((size_t)a * 384 + c) * 18 + k];
            else if (k >= 12 && k < 28) val = pp.wih[((size_t)a * 384 + c) * 18 + (k - 10)];
            else if (k >= 32)           val = pp.whh[((size_t)a * 384 + c) * 128 + (k - 32)];
        } else {
            const float* s = (job == 4) ? pp.eW2 : (job == 5) ? pp.pW2 : (job == 6) ? pp.dW2
                           : (job <= 10) ? pp.hW[job - 7] : pp.dHW[job - 11];
            val = s[((size_t)a * 128 + k) * od + c];
        }
        v[i] = val;
    }
    u32 lo = (u32)f2h(v[0]) | ((u32)f2h(v[1]) << 16);
    u32 hi = (u32)f2h(v[2]) | ((u32)f2h(v[3]) << 16);
    pp.dst[(size_t)a * AGU2 + jdst[job] + q * od + c] = make_uint2(lo, hi);
}

__global__ void finish_kernel(const float* __restrict__ partials, float* __restrict__ out) {
    __shared__ float red[256];
    int tid = threadIdx.x;
    red[tid] = (tid < NWG) ? partials[tid] : 0.f;
    __syncthreads();
    for (int s2 = 128; s2 > 0; s2 >>= 1) {
        if (tid < s2) red[tid] += red[tid + s2];
        __syncthreads();
    }
    if (tid == 0) out[0] = red[0];
    __syncthreads();
    red[tid] = (tid < NWG) ? partials[NWG + tid] : 0.f;
    __syncthreads();
    for (int s2 = 128; s2 > 0; s2 >>= 1) {
        if (tid < s2) red[tid] += red[tid + s2];
        __syncthreads();
    }
    if (tid == 0) out[1] = red[0];
}

extern "C" void kernel_launch(void* const* d_in, const int* in_sizes, int n_in,
                              void* d_out, int out_size, void* d_ws, size_t ws_size,
                              hipStream_t stream) {
    float* partials = (float*)d_ws;                 // 320 floats
    uint2* wq = (uint2*)((char*)d_ws + 4096);       // packed weights, ~1.81 MB

    PrepP pp;
    pp.eW1 = (const float*)d_in[2];
    pp.pW1 = (const float*)d_in[10];
    pp.dW1 = (const float*)d_in[18];
    pp.wih = (const float*)d_in[26];
    pp.whh = (const float*)d_in[27];
    pp.eW2 = (const float*)d_in[4];
    pp.pW2 = (const float*)d_in[12];
    pp.dW2 = (const float*)d_in[20];
    pp.hW[0] = (const float*)d_in[6];   // emW
    pp.hW[1] = (const float*)d_in[8];   // esW
    pp.hW[2] = (const float*)d_in[14];  // pmW
    pp.hW[3] = (const float*)d_in[16];  // psW
    pp.dHW[0] = (const float*)d_in[22]; // dmW
    pp.dHW[1] = (const float*)d_in[24]; // dsW
    pp.dst = wq;
    prep3<<<dim3(300, 13), 256, 0, stream>>>(pp);

    P7s p;
    p.y   = (const float*)d_in[0];
    p.eps = (const float*)d_in[1];
    p.eb1 = (const float*)d_in[3];  p.eb2 = (const float*)d_in[5];
    p.emb = (const float*)d_in[7];  p.esb = (const float*)d_in[9];
    p.pb1 = (const float*)d_in[11]; p.pb2 = (const float*)d_in[13];
    p.pmb = (const float*)d_in[15]; p.psb = (const float*)d_in[17];
    p.db1 = (const float*)d_in[19]; p.db2 = (const float*)d_in[21];
    p.dmb = (const float*)d_in[23]; p.dsb = (const float*)d_in[25];
    p.bih = (const float*)d_in[28]; p.bhh = (const float*)d_in[29];
    p.wq = wq;
    p.partials = partials;

    vrnn7<<<NWG, NTH, 0, stream>>>(p);
    finish_kernel<<<1, 256, 0, stream>>>(partials, (float*)d_out);
}